// Round 9
// baseline (235.225 us; speedup 1.0000x reference)
//
#include <hip/hip_runtime.h>
#include <hip/hip_bf16.h>

#define N_B   16
#define CIO   512
#define LSEQ  384
#define DH    64
#define NH    8
#define CHID  512
#define ME    384
#define DG    8

typedef __hip_bfloat16 bf16;
typedef __attribute__((ext_vector_type(8))) short bf16x8;
typedef __attribute__((ext_vector_type(4))) float f32x4;

__device__ __forceinline__ unsigned short f2bs(float f) {
    union { bf16 b; unsigned short u; } cv; cv.b = __float2bfloat16(f); return cv.u;
}

// ---------------------------------------------------------------------------
// wconv: cast 4 weight matrices (512x512 fp32) to bf16. 8 elems/thread.
// ---------------------------------------------------------------------------
__launch_bounds__(256)
__global__ void wconv_kernel(const float* __restrict__ w0, const float* __restrict__ w1,
                             const float* __restrict__ w2, const float* __restrict__ w3,
                             bf16* __restrict__ d0, bf16* __restrict__ d1,
                             bf16* __restrict__ d2, bf16* __restrict__ d3)
{
    int e = (blockIdx.x * 256 + threadIdx.x) * 8;
    int which = e >> 18;                  // 262144 elems per matrix
    int off = e & ((1 << 18) - 1);
    const float* s = which == 0 ? w0 : which == 1 ? w1 : which == 2 ? w2 : w3;
    bf16* d       = which == 0 ? d0 : which == 1 ? d1 : which == 2 ? d2 : d3;
    float4 f0 = *(const float4*)&s[off];
    float4 f1 = *(const float4*)&s[off + 4];
    unsigned short u[8] = {f2bs(f0.x), f2bs(f0.y), f2bs(f0.z), f2bs(f0.w),
                           f2bs(f1.x), f2bs(f1.y), f2bs(f1.z), f2bs(f1.w)};
    *(uint4*)&d[off] = *(uint4*)u;
}

// ---------------------------------------------------------------------------
// prep: X1 = x + qkorg*xorg + qkpos*abspos, X0 = x + vorg*xorg (fp32 math),
// write both bf16 TRANSPOSED [n][l][c]. 64c x 64l tile per block via LDS.
// ALSO: per-c-block partial gate into gpart[cb][n][h][l] (no atomics).
// ---------------------------------------------------------------------------
__launch_bounds__(256)
__global__ void prep_kernel(const float* __restrict__ x, const float* __restrict__ xorg,
                            const float* __restrict__ abspos,
                            const float* __restrict__ qkorg, const float* __restrict__ qkpos,
                            const float* __restrict__ vorg,
                            const float* __restrict__ gw,
                            bf16* __restrict__ x1t, bf16* __restrict__ x0t,
                            float* __restrict__ gpart)
{
    __shared__ bf16 T1[64 * 72], T0[64 * 72];   // [l][c], rows padded to 72
    __shared__ float Traw[64 * 65];             // [c][l] fp32, stride 65
    __shared__ float gws[NH * 64];              // gate_w slice [h][c_local]
    __shared__ float r0[64], r1[64], r2[64];
    const int tid = threadIdx.x;
    const int cb = blockIdx.x;
    const int c0 = cb * 64;
    const int l0 = blockIdx.y * 64;
    const int n  = blockIdx.z;
    if (tid < 64) {
        int gidx = (c0 + tid) >> 3;
        r0[tid] = vorg[gidx];
        r1[tid] = qkorg[gidx];
        r2[tid] = qkpos[gidx];
    }
    for (int t = tid; t < NH * 64; t += 256) {
        int h = t >> 6, c = t & 63;
        gws[t] = gw[h * CIO + c0 + c];
    }
    __syncthreads();
    const int l = tid & 63, cs = tid >> 6;
    #pragma unroll
    for (int r = 0; r < 16; r++) {
        int cl = r * 4 + cs;
        size_t gi = ((size_t)n * CIO + c0 + cl) * LSEQ + l0 + l;
        float xv = x[gi], xo = xorg[gi];
        Traw[cl * 65 + l] = xv;
        T0[l * 72 + cl] = __float2bfloat16(xv + r0[cl] * xo);
        T1[l * 72 + cl] = __float2bfloat16(xv + r1[cl] * xo + r2[cl] * abspos[gi]);
    }
    __syncthreads();
    for (int t = tid; t < NH * 64; t += 256) {
        int h = t >> 6, ll = t & 63;
        float s = 0.f;
        #pragma unroll
        for (int c = 0; c < 64; c++) s += gws[h * 64 + c] * Traw[c * 65 + ll];
        gpart[(((size_t)cb * N_B + n) * NH + h) * LSEQ + l0 + ll] = s;
    }
    #pragma unroll
    for (int t = 0; t < 2; t++) {
        int idx = t * 256 + tid;
        int lr = idx >> 3, u = idx & 7;
        size_t go = ((size_t)n * LSEQ + l0 + lr) * CIO + c0 + u * 8;
        *(uint4*)&x1t[go] = *(const uint4*)&T1[lr * 72 + u * 8];
        *(uint4*)&x0t[go] = *(const uint4*)&T0[lr * 72 + u * 8];
    }
}

// ---------------------------------------------------------------------------
// Merged MFMA GEMM for q/k (fused, shared B=x1t) and v. 1D grid of 768.
// XCD swizzle preserved. Tile 64(o) x 128(l); 3-stage register prefetch
// (2 k-steps ahead ~ 160cy MFMA cover vs ~200cy L2 latency).
// ---------------------------------------------------------------------------
__launch_bounds__(256, 2)
__global__ void mgemm_qkv_kernel(const bf16* __restrict__ wq, const bf16* __restrict__ wk,
                                 const bf16* __restrict__ wv,
                                 const bf16* __restrict__ x1t, const bf16* __restrict__ x0t,
                                 bf16* __restrict__ qb, bf16* __restrict__ kb,
                                 bf16* __restrict__ vb)
{
    __shared__ __align__(16) char smem[36864];
    const int tid = threadIdx.x;
    const int lane = tid & 63, w = tid >> 6;
    const int l15 = lane & 15, g = lane >> 4;
    const int Bid = blockIdx.x;
    const int rres = Bid & 7, qq = Bid >> 3;          // qq 0..95
    const int slice = rres + 8 * (qq / 24);           // 0..31
    const int within = qq % 24;
    const int which = slice >> 4;                     // 0 = qk fused, 1 = v
    const int n = slice & 15;
    const int l0 = (within % 3) * 128;
    const int o0 = (within / 3) * 64;

    if (which == 0) {
        // ---------------- fused q+k ----------------
        f32x4 accq[4][2], acck[4][2];
        #pragma unroll
        for (int mt = 0; mt < 4; mt++)
            #pragma unroll
            for (int jt = 0; jt < 2; jt++) {
                accq[mt][jt] = f32x4{0.f, 0.f, 0.f, 0.f};
                acck[mt][jt] = f32x4{0.f, 0.f, 0.f, 0.f};
            }
        const bf16* aqrow = wq + (size_t)(o0 + l15) * CIO + 8 * g;
        const bf16* akrow = wk + (size_t)(o0 + l15) * CIO + 8 * g;
        const bf16* brow  = x1t + ((size_t)n * LSEQ + l0 + w * 32 + l15) * CIO + 8 * g;

        bf16x8 aq[3][4], ak[3][4], bb[3][2];
        #pragma unroll
        for (int p = 0; p < 2; p++) {
            const int kk = p * 32;
            #pragma unroll
            for (int mt = 0; mt < 4; mt++) {
                aq[p][mt] = *(const bf16x8*)&aqrow[(size_t)mt * 16 * CIO + kk];
                ak[p][mt] = *(const bf16x8*)&akrow[(size_t)mt * 16 * CIO + kk];
            }
            #pragma unroll
            for (int jt = 0; jt < 2; jt++)
                bb[p][jt] = *(const bf16x8*)&brow[(size_t)jt * 16 * CIO + kk];
        }

        #pragma unroll
        for (int it = 0; it < 16; it++) {
            const int s = it % 3, pf = (it + 2) % 3;
            if (it < 14) {
                const int kn = (it + 2) * 32;
                #pragma unroll
                for (int mt = 0; mt < 4; mt++) {
                    aq[pf][mt] = *(const bf16x8*)&aqrow[(size_t)mt * 16 * CIO + kn];
                    ak[pf][mt] = *(const bf16x8*)&akrow[(size_t)mt * 16 * CIO + kn];
                }
                #pragma unroll
                for (int jt = 0; jt < 2; jt++)
                    bb[pf][jt] = *(const bf16x8*)&brow[(size_t)jt * 16 * CIO + kn];
            }
            #pragma unroll
            for (int mt = 0; mt < 4; mt++)
                #pragma unroll
                for (int jt = 0; jt < 2; jt++) {
                    accq[mt][jt] = __builtin_amdgcn_mfma_f32_16x16x32_bf16(aq[s][mt], bb[s][jt], accq[mt][jt], 0, 0, 0);
                    acck[mt][jt] = __builtin_amdgcn_mfma_f32_16x16x32_bf16(ak[s][mt], bb[s][jt], acck[mt][jt], 0, 0, 0);
                }
        }

        // epilogue: Sq | Sk, one barrier, coalesced 16B stores
        bf16* Sq = (bf16*)smem;              // [128 l][72]
        bf16* Sk = (bf16*)(smem + 18432);
        #pragma unroll
        for (int mt = 0; mt < 4; mt++)
            #pragma unroll
            for (int jt = 0; jt < 2; jt++)
                #pragma unroll
                for (int r = 0; r < 4; r++) {
                    int row = (w * 32 + jt * 16 + l15) * 72 + mt * 16 + 4 * g + r;
                    Sq[row] = __float2bfloat16(accq[mt][jt][r]);
                    Sk[row] = __float2bfloat16(acck[mt][jt][r]);
                }
        __syncthreads();
        bf16* qg = qb + ((size_t)n * NH + (o0 >> 6)) * LSEQ * DH + (size_t)l0 * DH;
        bf16* kg = kb + ((size_t)n * NH + (o0 >> 6)) * LSEQ * DH + (size_t)l0 * DH;
        #pragma unroll
        for (int t = 0; t < 4; t++) {
            int idx = t * 256 + tid;
            int lr = idx >> 3, u = idx & 7;
            *(uint4*)&qg[(size_t)lr * DH + u * 8] = *(const uint4*)&Sq[lr * 72 + u * 8];
            *(uint4*)&kg[(size_t)lr * DH + u * 8] = *(const uint4*)&Sk[lr * 72 + u * 8];
        }
    } else {
        // ---------------- v ----------------
        f32x4 acc[4][2];
        #pragma unroll
        for (int mt = 0; mt < 4; mt++)
            #pragma unroll
            for (int jt = 0; jt < 2; jt++) acc[mt][jt] = f32x4{0.f, 0.f, 0.f, 0.f};
        const bf16* arow = wv + (size_t)(o0 + l15) * CIO + 8 * g;
        const bf16* brow = x0t + ((size_t)n * LSEQ + l0 + w * 32 + l15) * CIO + 8 * g;

        bf16x8 a[3][4], bb[3][2];
        #pragma unroll
        for (int p = 0; p < 2; p++) {
            const int kk = p * 32;
            #pragma unroll
            for (int mt = 0; mt < 4; mt++)
                a[p][mt] = *(const bf16x8*)&arow[(size_t)mt * 16 * CIO + kk];
            #pragma unroll
            for (int jt = 0; jt < 2; jt++)
                bb[p][jt] = *(const bf16x8*)&brow[(size_t)jt * 16 * CIO + kk];
        }

        #pragma unroll
        for (int it = 0; it < 16; it++) {
            const int s = it % 3, pf = (it + 2) % 3;
            if (it < 14) {
                const int kn = (it + 2) * 32;
                #pragma unroll
                for (int mt = 0; mt < 4; mt++)
                    a[pf][mt] = *(const bf16x8*)&arow[(size_t)mt * 16 * CIO + kn];
                #pragma unroll
                for (int jt = 0; jt < 2; jt++)
                    bb[pf][jt] = *(const bf16x8*)&brow[(size_t)jt * 16 * CIO + kn];
            }
            #pragma unroll
            for (int mt = 0; mt < 4; mt++)
                #pragma unroll
                for (int jt = 0; jt < 2; jt++)
                    acc[mt][jt] = __builtin_amdgcn_mfma_f32_16x16x32_bf16(a[s][mt], bb[s][jt], acc[mt][jt], 0, 0, 0);
        }

        bf16* S = (bf16*)smem;   // [64 o][136]
        #pragma unroll
        for (int mt = 0; mt < 4; mt++)
            #pragma unroll
            for (int jt = 0; jt < 2; jt++)
                #pragma unroll
                for (int r = 0; r < 4; r++)
                    S[(mt * 16 + 4 * g + r) * 136 + w * 32 + jt * 16 + l15] =
                        __float2bfloat16(acc[mt][jt][r]);
        __syncthreads();
        bf16* og = vb + ((size_t)n * CHID + o0) * LSEQ + l0;
        #pragma unroll
        for (int t = 0; t < 4; t++) {
            int idx = t * 256 + tid;
            int orow = idx >> 4, u = idx & 15;
            *(uint4*)&og[(size_t)orow * LSEQ + u * 8] = *(const uint4*)&S[orow * 136 + u * 8];
        }
    }
}

// ---------------------------------------------------------------------------
// Dense MFMA GEMM, XCD-swizzled 1D grid of 384, 3-stage prefetch.
// ---------------------------------------------------------------------------
__launch_bounds__(256, 2)
__global__ void mgemm_dense_kernel(const bf16* __restrict__ Wb,
                                   const bf16* __restrict__ Bt,
                                   const float* __restrict__ bias,
                                   float* __restrict__ outf)
{
    __shared__ __align__(16) float S[64 * 132];
    const int tid = threadIdx.x;
    const int lane = tid & 63, w = tid >> 6;
    const int l15 = lane & 15, g = lane >> 4;
    const int Bid = blockIdx.x;
    const int rres = Bid & 7, qq = Bid >> 3;   // qq 0..47
    const int n = rres + 8 * (qq / 24);        // 0..15
    const int within = qq % 24;
    const int l0 = (within % 3) * 128;
    const int o0 = (within / 3) * 64;

    f32x4 acc[4][2];
    #pragma unroll
    for (int mt = 0; mt < 4; mt++)
        #pragma unroll
        for (int jt = 0; jt < 2; jt++) acc[mt][jt] = f32x4{0.f, 0.f, 0.f, 0.f};

    const bf16* arow = Wb + (size_t)(o0 + l15) * CIO + 8 * g;
    const bf16* brow = Bt + ((size_t)n * LSEQ + l0 + w * 32 + l15) * CIO + 8 * g;

    bf16x8 a[3][4], bb[3][2];
    #pragma unroll
    for (int p = 0; p < 2; p++) {
        const int kk = p * 32;
        #pragma unroll
        for (int mt = 0; mt < 4; mt++)
            a[p][mt] = *(const bf16x8*)&arow[(size_t)mt * 16 * CIO + kk];
        #pragma unroll
        for (int jt = 0; jt < 2; jt++)
            bb[p][jt] = *(const bf16x8*)&brow[(size_t)jt * 16 * CIO + kk];
    }

    #pragma unroll
    for (int it = 0; it < 16; it++) {
        const int s = it % 3, pf = (it + 2) % 3;
        if (it < 14) {
            const int kn = (it + 2) * 32;
            #pragma unroll
            for (int mt = 0; mt < 4; mt++)
                a[pf][mt] = *(const bf16x8*)&arow[(size_t)mt * 16 * CIO + kn];
            #pragma unroll
            for (int jt = 0; jt < 2; jt++)
                bb[pf][jt] = *(const bf16x8*)&brow[(size_t)jt * 16 * CIO + kn];
        }
        #pragma unroll
        for (int mt = 0; mt < 4; mt++)
            #pragma unroll
            for (int jt = 0; jt < 2; jt++)
                acc[mt][jt] = __builtin_amdgcn_mfma_f32_16x16x32_bf16(a[s][mt], bb[s][jt], acc[mt][jt], 0, 0, 0);
    }

    #pragma unroll
    for (int mt = 0; mt < 4; mt++) {
        #pragma unroll
        for (int r = 0; r < 4; r++) {
            float bv = bias[o0 + mt * 16 + 4 * g + r];
            #pragma unroll
            for (int jt = 0; jt < 2; jt++)
                S[(mt * 16 + 4 * g + r) * 132 + w * 32 + jt * 16 + l15] =
                    acc[mt][jt][r] + bv;
        }
    }
    __syncthreads();
    float* og = outf + ((size_t)n * CHID + o0) * LSEQ + l0;
    #pragma unroll
    for (int t = 0; t < 8; t++) {
        int idx = t * 256 + tid;
        int orow = idx >> 5, u = idx & 31;
        *(uint4*)&og[(size_t)orow * LSEQ + u * 4] = *(const uint4*)&S[orow * 132 + u * 4];
    }
}

// ---------------------------------------------------------------------------
// MFMA attention, XCD-swizzled 1D grid of 768 (residue = h).
// Phase 1: K B-frags DIRECT from global (kt already in B-frag layout) —
// no LDS staging, no barrier, 48 independent 16B loads for ILP.
// Phase 2: V B-frags global with 2-stage register prefetch.
// LDS: P[64][392] bf16 (reused as O[64][72]) + relp + radd.
// ---------------------------------------------------------------------------
__launch_bounds__(256, 2)
__global__ void attn2_kernel(const bf16* __restrict__ qt,   // [n][h][i][d]
                             const bf16* __restrict__ kt,   // [n][h][j][d]
                             const bf16* __restrict__ v,    // [n][h*64+d][j]
                             const float* __restrict__ gpart,
                             const float* __restrict__ gb,
                             const float* __restrict__ mask,
                             const float* __restrict__ norm,
                             const float* __restrict__ relpos,
                             bf16* __restrict__ ctxt)
{
    __shared__ __align__(16) char smem[50176];   // P[64][392] bf16 | O[64][72]
    __shared__ float relp_s[2 * ME - 1];
    __shared__ float radd_s[LSEQ];

    bf16* P = (bf16*)smem;
    bf16* O = (bf16*)smem;

    const int tid = threadIdx.x;
    const int Bid = blockIdx.x;
    const int h = Bid & 7, qq = Bid >> 3;   // qq 0..95
    const int n = qq / 6;
    const int i0 = (qq % 6) * 64;
    const int lane = tid & 63;
    const int w = tid >> 6;
    const int l15 = lane & 15, g = lane >> 4;
    const int m0 = w * 16;

    const size_t nh = (size_t)n * NH + h;
    const bf16* kt_g = kt + nh * LSEQ * DH;
    const bf16* vg   = v + ((size_t)n * CHID + h * DH) * LSEQ;

    {
        const float gbh = gb[h];
        for (int i = tid; i < LSEQ; i += 256) {
            float s = gbh + mask[(size_t)n * LSEQ + i];
            #pragma unroll
            for (int cb = 0; cb < 8; cb++)
                s += gpart[(((size_t)cb * N_B + n) * NH + h) * LSEQ + i];
            radd_s[i] = s;
        }
    }
    for (int i = tid; i < 2 * ME - 1; i += 256) relp_s[i] = relpos[i];

    const bf16* qrow = qt + (nh * LSEQ + i0 + m0 + l15) * DH;
    bf16x8 a0 = *(const bf16x8*)&qrow[8 * g];
    bf16x8 a1 = *(const bf16x8*)&qrow[8 * g + 32];
    const float inv_norm = 1.0f / norm[n];

    __syncthreads();   // radd_s/relp_s visible to all

    // ---- Phase 1: S = Q K^T, K frags direct from global ----
    f32x4 acc[24];
    #pragma unroll
    for (int jt = 0; jt < 24; jt++) acc[jt] = f32x4{0.f, 0.f, 0.f, 0.f};
    #pragma unroll
    for (int jt = 0; jt < 24; jt++) {
        const bf16* kr = &kt_g[(size_t)(jt * 16 + l15) * DH + 8 * g];
        bf16x8 b0 = *(const bf16x8*)kr;
        bf16x8 b1 = *(const bf16x8*)(kr + 32);
        acc[jt] = __builtin_amdgcn_mfma_f32_16x16x32_bf16(a0, b0, acc[jt], 0, 0, 0);
        acc[jt] = __builtin_amdgcn_mfma_f32_16x16x32_bf16(a1, b1, acc[jt], 0, 0, 0);
    }

    // ---- softmax over full rows; row i_loc = m0 + 4g + r ----
    const int ib = i0 + m0 + 4 * g;
    float mx[4] = {-1e30f, -1e30f, -1e30f, -1e30f};
    #pragma unroll
    for (int jt = 0; jt < 24; jt++) {
        float ra = radd_s[jt * 16 + l15];
        #pragma unroll
        for (int r = 0; r < 4; r++) {
            int idx = ME - (ib + r) + jt * 16 + l15;
            idx = (idx > 2 * ME - 2) ? (2 * ME - 2) : idx;
            float s = (acc[jt][r] + relp_s[idx] + ra) * inv_norm;
            acc[jt][r] = s;
            mx[r] = fmaxf(mx[r], s);
        }
    }
    #pragma unroll
    for (int r = 0; r < 4; r++)
        #pragma unroll
        for (int off = 1; off <= 8; off <<= 1)
            mx[r] = fmaxf(mx[r], __shfl_xor(mx[r], off));
    float sm[4] = {0.f, 0.f, 0.f, 0.f};
    #pragma unroll
    for (int jt = 0; jt < 24; jt++) {
        #pragma unroll
        for (int r = 0; r < 4; r++) {
            float e = __expf(acc[jt][r] - mx[r]);
            acc[jt][r] = e;
            sm[r] += e;
        }
    }
    #pragma unroll
    for (int r = 0; r < 4; r++) {
        #pragma unroll
        for (int off = 1; off <= 8; off <<= 1)
            sm[r] += __shfl_xor(sm[r], off);
        sm[r] = 1.0f / sm[r];
    }
    #pragma unroll
    for (int jt = 0; jt < 24; jt++)
        #pragma unroll
        for (int r = 0; r < 4; r++)
            P[(m0 + 4 * g + r) * 392 + jt * 16 + l15] =
                __float2bfloat16(acc[jt][r] * sm[r]);
    // each wave reads back only its own rows — no barrier

    // ---- Phase 2: O = P V^T, V frags prefetched 1 tile ahead ----
    f32x4 oacc[4];
    #pragma unroll
    for (int dn = 0; dn < 4; dn++) oacc[dn] = f32x4{0.f, 0.f, 0.f, 0.f};
    bf16x8 vreg[2][4];
    #pragma unroll
    for (int dn = 0; dn < 4; dn++)
        vreg[0][dn] = *(const bf16x8*)&vg[(size_t)(dn * 16 + l15) * LSEQ + 8 * g];
    #pragma unroll
    for (int jt2 = 0; jt2 < 12; jt2++) {
        const int s = jt2 & 1;
        if (jt2 < 11) {
            #pragma unroll
            for (int dn = 0; dn < 4; dn++)
                vreg[s ^ 1][dn] = *(const bf16x8*)&vg[(size_t)(dn * 16 + l15) * LSEQ + (jt2 + 1) * 32 + 8 * g];
        }
        bf16x8 a = *(const bf16x8*)&P[(m0 + l15) * 392 + jt2 * 32 + 8 * g];
        #pragma unroll
        for (int dn = 0; dn < 4; dn++)
            oacc[dn] = __builtin_amdgcn_mfma_f32_16x16x32_bf16(a, vreg[s][dn], oacc[dn], 0, 0, 0);
    }

    __syncthreads();   // P reads done; smem becomes O [i_loc][72]
    #pragma unroll
    for (int dn = 0; dn < 4; dn++)
        #pragma unroll
        for (int r = 0; r < 4; r++)
            O[(m0 + 4 * g + r) * 72 + dn * 16 + l15] = __float2bfloat16(oacc[dn][r]);
    __syncthreads();

    bf16* cg = ctxt + ((size_t)n * LSEQ + i0) * CHID + h * DH;
    #pragma unroll
    for (int t = 0; t < 2; t++) {
        int idx = t * 256 + tid;
        int ir = idx >> 3, u = idx & 7;
        *(uint4*)&cg[(size_t)ir * CHID + u * 8] = *(const uint4*)&O[ir * 72 + u * 8];
    }
}

// ---------------------------------------------------------------------------
extern "C" void kernel_launch(void* const* d_in, const int* in_sizes, int n_in,
                              void* d_out, int out_size, void* d_ws, size_t ws_size,
                              hipStream_t stream)
{
    const float* x       = (const float*)d_in[0];
    const float* xorg    = (const float*)d_in[1];
    const float* abspos  = (const float*)d_in[2];
    const float* mask    = (const float*)d_in[3];
    const float* norm    = (const float*)d_in[4];
    const float* qkpos   = (const float*)d_in[5];
    const float* qkorg   = (const float*)d_in[6];
    const float* vorg    = (const float*)d_in[7];
    const float* relpos  = (const float*)d_in[8];
    const float* gate_w  = (const float*)d_in[9];
    const float* gate_b  = (const float*)d_in[10];
    const float* q_w     = (const float*)d_in[11];
    const float* k_w     = (const float*)d_in[12];
    const float* v_w     = (const float*)d_in[13];
    const float* dense_w = (const float*)d_in[14];
    const float* dense_b = (const float*)d_in[15];
    float* out = (float*)d_out;

    const size_t TEN = (size_t)N_B * CHID * LSEQ * sizeof(bf16);  // 6291456 B
    const size_t WB  = (size_t)CHID * CIO * sizeof(bf16);          // 524288 B
    char* ws = (char*)d_ws;
    bf16*  x1t  = (bf16*)(ws);                 // [n][l][c]; aliased by ctxt later
    bf16*  x0t  = (bf16*)(ws + TEN);           // [n][l][c]
    bf16*  qb   = (bf16*)(ws + 2 * TEN);       // [n][h][i][d]
    bf16*  kb   = (bf16*)(ws + 3 * TEN);       // [n][h][j][d]
    bf16*  vb   = (bf16*)(ws + 4 * TEN);       // [n][c][l]
    bf16*  wqb  = (bf16*)(ws + 5 * TEN);
    bf16*  wkb  = (bf16*)(ws + 5 * TEN + WB);
    bf16*  wvb  = (bf16*)(ws + 5 * TEN + 2 * WB);
    bf16*  wdb  = (bf16*)(ws + 5 * TEN + 3 * WB);
    float* gpart = (float*)(ws + 5 * TEN + 4 * WB);  // [8][16][8][384] fp32, 1.57 MB
    bf16*  ctxt = x1t;   // x1t dead after q,k GEMMs; attn runs after them

    wconv_kernel<<<512, 256, 0, stream>>>(q_w, k_w, v_w, dense_w, wqb, wkb, wvb, wdb);
    prep_kernel<<<dim3(CIO / 64, LSEQ / 64, N_B), 256, 0, stream>>>(
        x, xorg, abspos, qkorg, qkpos, vorg, gate_w, x1t, x0t, gpart);
    mgemm_qkv_kernel<<<768, 256, 0, stream>>>(wqb, wkb, wvb, x1t, x0t, qb, kb, vb);
    attn2_kernel<<<768, 256, 0, stream>>>(qb, kb, vb, gpart, gate_b,
                                          mask, norm, relpos, ctxt);
    mgemm_dense_kernel<<<384, 256, 0, stream>>>(wdb, ctxt, dense_b, out);
}